// Round 3
// baseline (976.565 us; speedup 1.0000x reference)
//
#include <hip/hip_runtime.h>

typedef __bf16 bf16;
typedef __attribute__((ext_vector_type(8))) __bf16 bf16x8;
typedef __attribute__((ext_vector_type(4))) float f32x4;

#define N_TOK 16384
#define DMODEL 1024
#define FDIM 4096
#define NHEAD 16

// ---------------------------------------------------------------- helpers
__device__ __forceinline__ void gload_lds16(const bf16* g, bf16* l) {
  __builtin_amdgcn_global_load_lds(
      (const __attribute__((address_space(1))) void*)g,
      (__attribute__((address_space(3))) void*)l,
      16, 0, 0);
}

__device__ __forceinline__ float gelu_tanh(float x) {
  return 0.5f * x * (1.0f + tanhf(0.7978845608028654f * (x + 0.044715f * x * x * x)));
}

// ---------------------------------------------------------------- fp32 -> bf16 copy
// n must be a multiple of 2048; grid = n/2048, block = 256
__global__ __launch_bounds__(256) void cvt_copy(const float* __restrict__ x,
                                                bf16* __restrict__ y) {
  size_t i = ((size_t)blockIdx.x * 256 + threadIdx.x) * 8;
  float4 a = *(const float4*)(x + i);
  float4 b = *(const float4*)(x + i + 4);
  bf16x8 o;
  o[0] = (bf16)a.x; o[1] = (bf16)a.y; o[2] = (bf16)a.z; o[3] = (bf16)a.w;
  o[4] = (bf16)b.x; o[5] = (bf16)b.y; o[6] = (bf16)b.z; o[7] = (bf16)b.w;
  *(bf16x8*)(y + i) = o;
}

// ---------------------------------------------------------------- convert+transpose
// dst[c][r] = (bf16)src[r][c]; R,C multiples of 32. block (32,8), grid (C/32, R/32)
__global__ void convt(const float* __restrict__ src, bf16* __restrict__ dst,
                      int R, int C) {
  __shared__ float tile[32][33];
  int c0 = blockIdx.x * 32, r0 = blockIdx.y * 32;
  int tx = threadIdx.x, ty = threadIdx.y;
#pragma unroll
  for (int i = 0; i < 4; ++i)
    tile[ty * 4 + i][tx] = src[(size_t)(r0 + ty * 4 + i) * C + c0 + tx];
  __syncthreads();
#pragma unroll
  for (int i = 0; i < 4; ++i)
    dst[(size_t)(c0 + ty * 4 + i) * R + r0 + tx] = (bf16)tile[tx][ty * 4 + i];
}

// ---------------------------------------------------------------- GEMM (B^T)
// C[M][N] = A[M][K] @ BT[N][K]^T + bias (+res) (+gelu); output bf16.
// RES: 0 = none, 1 = fp32 residual, 2 = bf16 residual.  GELU: 0/1.
#define BM 128
#define BN 128
#define BK 32

template <int RES, int GELU>
__global__ __launch_bounds__(256) void gemm_bt(
    const bf16* __restrict__ A, const bf16* __restrict__ BT,
    const float* __restrict__ bias, const float* __restrict__ resf,
    const bf16* __restrict__ resb, bf16* __restrict__ C,
    int M, int N, int K) {
  __shared__ alignas(16) bf16 lA[BM * BK];
  __shared__ alignas(16) bf16 lB[BN * BK];
  const int tid = threadIdx.x;
  const int nbn = N / BN;
  const int bm = blockIdx.x / nbn, bn = blockIdx.x % nbn;
  const int row0 = bm * BM, col0 = bn * BN;
  const int lane = tid & 63, wave = tid >> 6;
  const int wr = wave >> 1, wc = wave & 1;  // 2x2 waves, 64x64 out each
  const int r16 = lane & 15, hk = lane >> 4;

  f32x4 acc[4][4] = {};

  for (int k0 = 0; k0 < K; k0 += BK) {
#pragma unroll
    for (int i = 0; i < 2; ++i) {
      int li = tid + i * 256;      // 0..511
      int r = li >> 2, sg = li & 3;
      gload_lds16(A + (size_t)(row0 + r) * K + k0 + sg * 8, lA + li * 8);
      gload_lds16(BT + (size_t)(col0 + r) * K + k0 + sg * 8, lB + li * 8);
    }
    __syncthreads();
    bf16x8 af[4], bfr[4];
#pragma unroll
    for (int m = 0; m < 4; ++m)
      af[m] = *(const bf16x8*)&lA[(wr * 64 + m * 16 + r16) * BK + hk * 8];
#pragma unroll
    for (int n = 0; n < 4; ++n)
      bfr[n] = *(const bf16x8*)&lB[(wc * 64 + n * 16 + r16) * BK + hk * 8];
#pragma unroll
    for (int m = 0; m < 4; ++m)
#pragma unroll
      for (int n = 0; n < 4; ++n)
        acc[m][n] = __builtin_amdgcn_mfma_f32_16x16x32_bf16(af[m], bfr[n], acc[m][n], 0, 0, 0);
    __syncthreads();
  }

#pragma unroll
  for (int m = 0; m < 4; ++m) {
#pragma unroll
    for (int n = 0; n < 4; ++n) {
#pragma unroll
      for (int r = 0; r < 4; ++r) {
        int row = row0 + wr * 64 + m * 16 + hk * 4 + r;
        int col = col0 + wc * 64 + n * 16 + r16;
        float v = acc[m][n][r] + bias[col];
        if (RES == 1) v += resf[(size_t)row * N + col];
        if (RES == 2) v += (float)resb[(size_t)row * N + col];
        if (GELU) v = gelu_tanh(v);
        C[(size_t)row * N + col] = (bf16)v;
      }
    }
  }
}

// ---------------------------------------------------------------- attention
// one block per (b,h); L=64, dh=64. q/k/v: [16384][1024] bf16, head h at cols h*64..
// ctx may alias q (each block reads its q slice into LDS before writing there).
__global__ __launch_bounds__(256) void attn_k(
    const bf16* q, const bf16* __restrict__ k,
    const bf16* __restrict__ v, const float* __restrict__ rel,
    bf16* ctx) {
  __shared__ alignas(16) bf16 lQ[64 * 64];
  __shared__ alignas(16) bf16 lK[64 * 64];
  __shared__ alignas(16) bf16 lVt[64 * 64];   // lVt[d][j] = v[j][d]
  __shared__ alignas(16) bf16 lP[4][16 * 64];
  __shared__ float lrel[128];

  const int bh = blockIdx.x;
  const int b = bh >> 4, h = bh & 15;
  const int tid = threadIdx.x;
  const size_t base = (size_t)(b * 64) * DMODEL + h * 64;

#pragma unroll
  for (int i = 0; i < 2; ++i) {
    int j = (tid >> 3) + i * 32;   // token row 0..63
    int d0 = (tid & 7) * 8;        // col start
    *(bf16x8*)&lQ[j * 64 + d0] = *(const bf16x8*)(q + base + (size_t)j * DMODEL + d0);
    *(bf16x8*)&lK[j * 64 + d0] = *(const bf16x8*)(k + base + (size_t)j * DMODEL + d0);
    bf16x8 vvv = *(const bf16x8*)(v + base + (size_t)j * DMODEL + d0);
#pragma unroll
    for (int u = 0; u < 8; ++u) lVt[(d0 + u) * 64 + j] = vvv[u];
  }
  if (tid < 127) lrel[tid] = rel[h * 127 + tid];
  __syncthreads();

  const int lane = tid & 63, w = tid >> 6;
  const int r16 = lane & 15, hk = lane >> 4;

  // S = Q K^T : wave w owns query rows w*16..w*16+15
  f32x4 s[4] = {};
#pragma unroll
  for (int dstep = 0; dstep < 2; ++dstep) {
    bf16x8 aq = *(const bf16x8*)&lQ[(w * 16 + r16) * 64 + dstep * 32 + hk * 8];
#pragma unroll
    for (int n = 0; n < 4; ++n) {
      bf16x8 bk_ = *(const bf16x8*)&lK[(n * 16 + r16) * 64 + dstep * 32 + hk * 8];
      s[n] = __builtin_amdgcn_mfma_f32_16x16x32_bf16(aq, bk_, s[n], 0, 0, 0);
    }
  }

  float p[16];
#pragma unroll
  for (int n = 0; n < 4; ++n)
#pragma unroll
    for (int r = 0; r < 4; ++r) {
      int i = w * 16 + hk * 4 + r;       // query row in L
      int j = n * 16 + r16;              // key col in L
      p[n * 4 + r] = s[n][r] * 0.125f + lrel[i - j + 63];
    }
  // softmax per row: row fixed by (hk,r); cols over n (regs) x r16 (16 lanes)
#pragma unroll
  for (int r = 0; r < 4; ++r) {
    float m = fmaxf(fmaxf(p[r], p[4 + r]), fmaxf(p[8 + r], p[12 + r]));
#pragma unroll
    for (int off = 1; off < 16; off <<= 1) m = fmaxf(m, __shfl_xor(m, off));
    float sum = 0.f;
#pragma unroll
    for (int n = 0; n < 4; ++n) {
      p[n * 4 + r] = __expf(p[n * 4 + r] - m);
      sum += p[n * 4 + r];
    }
#pragma unroll
    for (int off = 1; off < 16; off <<= 1) sum += __shfl_xor(sum, off);
    float inv = 1.0f / sum;
#pragma unroll
    for (int n = 0; n < 4; ++n) p[n * 4 + r] *= inv;
  }
  // P to LDS (C-layout -> A-frag layout transpose through LDS)
#pragma unroll
  for (int n = 0; n < 4; ++n)
#pragma unroll
    for (int r = 0; r < 4; ++r)
      lP[w][(hk * 4 + r) * 64 + n * 16 + r16] = (bf16)p[n * 4 + r];
  __syncthreads();

  // ctx = P V
  f32x4 o[4] = {};
#pragma unroll
  for (int ks = 0; ks < 2; ++ks) {
    bf16x8 ap = *(const bf16x8*)&lP[w][r16 * 64 + ks * 32 + hk * 8];
#pragma unroll
    for (int n = 0; n < 4; ++n) {
      bf16x8 bv_ = *(const bf16x8*)&lVt[(n * 16 + r16) * 64 + ks * 32 + hk * 8];
      o[n] = __builtin_amdgcn_mfma_f32_16x16x32_bf16(ap, bv_, o[n], 0, 0, 0);
    }
  }
#pragma unroll
  for (int n = 0; n < 4; ++n)
#pragma unroll
    for (int r = 0; r < 4; ++r) {
      int trow = b * 64 + w * 16 + hk * 4 + r;
      ctx[(size_t)trow * DMODEL + h * 64 + n * 16 + r16] = (bf16)o[n][r];
    }
}

// ---------------------------------------------------------------- layernorm
// one wave per row of 1024; block=256 -> 4 rows/block. F32OUT: write fp32 out.
template <int F32OUT>
__global__ __launch_bounds__(256) void layernorm_k(
    const bf16* __restrict__ x, const float* __restrict__ g,
    const float* __restrict__ be, bf16* __restrict__ ob,
    float* __restrict__ of) {
  int row = blockIdx.x * 4 + (threadIdx.x >> 6);
  int lane = threadIdx.x & 63;
  const bf16* xr = x + (size_t)row * DMODEL + lane * 16;
  bf16x8 v0 = *(const bf16x8*)xr;
  bf16x8 v1 = *(const bf16x8*)(xr + 8);
  float f[16];
#pragma unroll
  for (int j = 0; j < 8; ++j) { f[j] = (float)v0[j]; f[8 + j] = (float)v1[j]; }
  float s = 0.f, sq = 0.f;
#pragma unroll
  for (int j = 0; j < 16; ++j) { s += f[j]; sq += f[j] * f[j]; }
#pragma unroll
  for (int off = 1; off < 64; off <<= 1) {
    s += __shfl_xor(s, off);
    sq += __shfl_xor(sq, off);
  }
  float mean = s * (1.0f / DMODEL);
  float var = sq * (1.0f / DMODEL) - mean * mean;
  float rstd = rsqrtf(var + 1e-5f);
  const float* gp = g + lane * 16;
  const float* bp = be + lane * 16;
  if (F32OUT) {
    float* op = of + (size_t)row * DMODEL + lane * 16;
#pragma unroll
    for (int j = 0; j < 16; ++j)
      op[j] = (f[j] - mean) * rstd * gp[j] + bp[j];
  } else {
    bf16x8 o0, o1;
#pragma unroll
    for (int j = 0; j < 8; ++j) {
      o0[j] = (bf16)((f[j] - mean) * rstd * gp[j] + bp[j]);
      o1[j] = (bf16)((f[8 + j] - mean) * rstd * gp[8 + j] + bp[8 + j]);
    }
    bf16* op = ob + (size_t)row * DMODEL + lane * 16;
    *(bf16x8*)op = o0;
    *(bf16x8*)(op + 8) = o1;
  }
}

// ---------------------------------------------------------------- launch
extern "C" void kernel_launch(void* const* d_in, const int* in_sizes, int n_in,
                              void* d_out, int out_size, void* d_ws, size_t ws_size,
                              hipStream_t stream) {
  (void)in_sizes; (void)n_in; (void)out_size; (void)ws_size;
  const float* src = (const float*)d_in[0];
  const float* Wq  = (const float*)d_in[1];
  const float* bq  = (const float*)d_in[2];
  const float* Wk  = (const float*)d_in[3];
  const float* bk  = (const float*)d_in[4];
  const float* Wv  = (const float*)d_in[5];
  const float* bv  = (const float*)d_in[6];
  const float* Wo  = (const float*)d_in[7];
  const float* bo  = (const float*)d_in[8];
  const float* rel = (const float*)d_in[9];
  const float* W1  = (const float*)d_in[10];
  const float* b1  = (const float*)d_in[11];
  const float* W2  = (const float*)d_in[12];
  const float* b2  = (const float*)d_in[13];
  const float* g1  = (const float*)d_in[14];
  const float* be1 = (const float*)d_in[15];
  const float* g2  = (const float*)d_in[16];
  const float* be2 = (const float*)d_in[17];

  // ---- workspace plan: ws usage <= 88 MiB; d_out (64 MiB fp32) doubles as
  //      two 32-MiB bf16 scratch slots (dead before the final LN2 write). ----
  char* ws = (char*)d_ws;
  const size_t MiB = 1ull << 20;
  bf16* srcb = (bf16*)(ws + 0 * MiB);    // 32 MiB; later: y1, then y2
  bf16* WqT  = (bf16*)(ws + 32 * MiB);   // 2 MiB
  bf16* WkT  = (bf16*)(ws + 34 * MiB);   // 2 MiB
  bf16* WvT  = (bf16*)(ws + 36 * MiB);   // 2 MiB
  bf16* WoT  = (bf16*)(ws + 38 * MiB);   // 2 MiB
  bf16* W1T  = (bf16*)(ws + 40 * MiB);   // 8 MiB  [4096][1024]
  bf16* W2T  = (bf16*)(ws + 48 * MiB);   // 8 MiB  [1024][4096]
  bf16* qb   = (bf16*)(ws + 56 * MiB);   // 32 MiB; later: ctx, then FFN h-chunk
  bf16* kb   = (bf16*)d_out;                    // 32 MiB; later: x (LN1 out)
  bf16* vb   = (bf16*)((char*)d_out + 32 * MiB);// 32 MiB
  bf16* y1   = srcb;   // srcb dead after QKV gemms
  bf16* xb   = kb;     // K dead after attention
  bf16* y2   = srcb;   // y1 dead after LN1

  cvt_copy<<<(N_TOK * DMODEL) / 2048, 256, 0, stream>>>(src, srcb);
  dim3 tb(32, 8);
  convt<<<dim3(32, 32), tb, 0, stream>>>(Wq, WqT, 1024, 1024);
  convt<<<dim3(32, 32), tb, 0, stream>>>(Wk, WkT, 1024, 1024);
  convt<<<dim3(32, 32), tb, 0, stream>>>(Wv, WvT, 1024, 1024);
  convt<<<dim3(32, 32), tb, 0, stream>>>(Wo, WoT, 1024, 1024);
  convt<<<dim3(128, 32), tb, 0, stream>>>(W1, W1T, 1024, 4096);
  convt<<<dim3(32, 128), tb, 0, stream>>>(W2, W2T, 4096, 1024);

  const int gQKV = (N_TOK / BM) * (DMODEL / BN);   // 128*8 = 1024
  gemm_bt<0, 0><<<gQKV, 256, 0, stream>>>(srcb, WqT, bq, nullptr, nullptr, qb, N_TOK, DMODEL, DMODEL);
  gemm_bt<0, 0><<<gQKV, 256, 0, stream>>>(srcb, WkT, bk, nullptr, nullptr, kb, N_TOK, DMODEL, DMODEL);
  gemm_bt<0, 0><<<gQKV, 256, 0, stream>>>(srcb, WvT, bv, nullptr, nullptr, vb, N_TOK, DMODEL, DMODEL);

  // ctx overwrites qb in place (each block consumes its own q slice first)
  attn_k<<<256 * NHEAD, 256, 0, stream>>>(qb, kb, vb, rel, qb);

  // y1 = ctx @ Wo + bo + src (fp32 residual)  -> srcb slot
  gemm_bt<1, 0><<<gQKV, 256, 0, stream>>>(qb, WoT, bo, src, nullptr, y1, N_TOK, DMODEL, DMODEL);
  // x = LN1(y1) -> kb slot (bf16)
  layernorm_k<0><<<N_TOK / 4, 256, 0, stream>>>(y1, g1, be1, xb, nullptr);

  // FFN in 4 chunks of 4096 rows; h-chunk (4096x4096 bf16 = 32 MiB) in qb
  const int CH = 4096;
  const int gF1 = (CH / BM) * (FDIM / BN);     // 32*32 = 1024
  const int gF2 = (CH / BM) * (DMODEL / BN);   // 32*8  = 256
  for (int c = 0; c < 4; ++c) {
    const bf16* xc = xb + (size_t)c * CH * DMODEL;
    bf16* yc = y2 + (size_t)c * CH * DMODEL;
    gemm_bt<0, 1><<<gF1, 256, 0, stream>>>(xc, W1T, b1, nullptr, nullptr, qb, CH, FDIM, DMODEL);
    gemm_bt<2, 0><<<gF2, 256, 0, stream>>>(qb, W2T, b2, nullptr, xc, yc, CH, DMODEL, FDIM);
  }
  // out = LN2(y2): reads ws, writes all of d_out (fp32) -- x/y2 scratch dead
  layernorm_k<1><<<N_TOK / 4, 256, 0, stream>>>(y2, g2, be2, nullptr, (float*)d_out);
}

// Round 4
// 723.915 us; speedup vs baseline: 1.3490x; 1.3490x over previous
//
#include <hip/hip_runtime.h>

typedef __bf16 bf16;
typedef __attribute__((ext_vector_type(8))) __bf16 bf16x8;
typedef __attribute__((ext_vector_type(4))) __bf16 bf16x4;
typedef __attribute__((ext_vector_type(4))) float f32x4;

#define N_TOK 16384
#define DMODEL 1024
#define FDIM 4096
#define NHEAD 16

// ---------------------------------------------------------------- helpers
__device__ __forceinline__ void gload_lds16(const bf16* g, bf16* l) {
  __builtin_amdgcn_global_load_lds(
      (const __attribute__((address_space(1))) void*)g,
      (__attribute__((address_space(3))) void*)l,
      16, 0, 0);
}

__device__ __forceinline__ float gelu_tanh(float x) {
  return 0.5f * x * (1.0f + tanhf(0.7978845608028654f * (x + 0.044715f * x * x * x)));
}

// ---------------------------------------------------------------- fp32 -> bf16 copy
__global__ __launch_bounds__(256) void cvt_copy(const float* __restrict__ x,
                                                bf16* __restrict__ y) {
  size_t i = ((size_t)blockIdx.x * 256 + threadIdx.x) * 8;
  float4 a = *(const float4*)(x + i);
  float4 b = *(const float4*)(x + i + 4);
  bf16x8 o;
  o[0] = (bf16)a.x; o[1] = (bf16)a.y; o[2] = (bf16)a.z; o[3] = (bf16)a.w;
  o[4] = (bf16)b.x; o[5] = (bf16)b.y; o[6] = (bf16)b.z; o[7] = (bf16)b.w;
  *(bf16x8*)(y + i) = o;
}

// ---------------------------------------------------------------- convert+transpose
__global__ void convt(const float* __restrict__ src, bf16* __restrict__ dst,
                      int R, int C) {
  __shared__ float tile[32][33];
  int c0 = blockIdx.x * 32, r0 = blockIdx.y * 32;
  int tx = threadIdx.x, ty = threadIdx.y;
#pragma unroll
  for (int i = 0; i < 4; ++i)
    tile[ty * 4 + i][tx] = src[(size_t)(r0 + ty * 4 + i) * C + c0 + tx];
  __syncthreads();
#pragma unroll
  for (int i = 0; i < 4; ++i)
    dst[(size_t)(c0 + ty * 4 + i) * R + r0 + tx] = (bf16)tile[tx][ty * 4 + i];
}

// ---------------------------------------------------------------- 256x256 8-phase GEMM
// C[M][N] = A[M][K] @ BT[N][K]^T + bias (+res) (+gelu); output bf16.
// M%256==0, N%256==0, K%64==0, grid%8==0. 512 threads, 8 waves (2Mx4N).
// LDS 128 KiB double-buffered; T2 XOR-swizzle (row&7)<<4 on byte addr,
// linear gload_lds dest + inverse-swizzled global source (rule 21).

// stage 128 rows x 64 cols (16 KiB) of row-major [*][K] global into LDS region.
__device__ __forceinline__ void stage_half(const bf16* g, int ldg, bf16* region,
                                           int wv, int lane) {
#pragma unroll
  for (int j = 0; j < 2; ++j) {
    int c = wv * 2 + j;                       // 1 KiB chunk id, 0..15
    int r = c * 8 + (lane >> 3);              // local row 0..127
    int col = ((lane & 7) * 8) ^ ((r & 7) * 8);  // inverse-swizzled source col
    gload_lds16(g + (size_t)r * ldg + col, region + c * 512 + lane * 8);
  }
}

// swizzled fragment read: logical (row, kcol elements)
__device__ __forceinline__ bf16x8 frag_ld(const bf16* s, int row, int kc) {
  return *(const bf16x8*)(s + row * 64 + (kc ^ ((row & 7) * 8)));
}

template <int RES, int GELU>   // RES: 0 none, 1 fp32, 2 bf16
__global__ __launch_bounds__(512) void gemm256(
    const bf16* __restrict__ A, const bf16* __restrict__ BT,
    const float* __restrict__ bias, const float* __restrict__ resf,
    const bf16* __restrict__ resb, bf16* __restrict__ C,
    int M, int N, int K) {
  __shared__ alignas(16) bf16 sA[2][256 * 64];
  __shared__ alignas(16) bf16 sB[2][256 * 64];
  const int tid = threadIdx.x;
  const int lane = tid & 63, wv = tid >> 6;
  const int wr = wv >> 2, wc = wv & 3;        // 2 x 4 wave grid
  const int r16 = lane & 15, hk = lane >> 4;

  const int nbn = N >> 8;
  const int cpx = gridDim.x >> 3;             // grid % 8 == 0
  const int swz = ((int)blockIdx.x & 7) * cpx + ((int)blockIdx.x >> 3);
  const int row0 = (swz / nbn) << 8, col0 = (swz % nbn) << 8;

  const bf16* Ab = A + (size_t)row0 * K;
  const bf16* Bb = BT + (size_t)col0 * K;

  f32x4 acc[8][4] = {};
  bf16x8 aF[4][2], bF0[2][2], bF1[2][2];

  // prologue: stage K-tile 0 into buf0
  stage_half(Ab,                      K, &sA[0][0],        wv, lane);
  stage_half(Ab + 128 * (size_t)K,    K, &sA[0][128 * 64], wv, lane);
  stage_half(Bb,                      K, &sB[0][0],        wv, lane);
  stage_half(Bb + 128 * (size_t)K,    K, &sB[0][128 * 64], wv, lane);
  asm volatile("s_waitcnt vmcnt(0)" ::: "memory");
  __builtin_amdgcn_s_barrier();

  const int nt = K >> 6;
  for (int kt = 0; kt < nt; ++kt) {
    const bf16* sa = &sA[kt & 1][0];
    const bf16* sb = &sB[kt & 1][0];
    bf16* na = &sA[(kt + 1) & 1][0];
    bf16* nb = &sB[(kt + 1) & 1][0];
    const bool pf = (kt + 1 < nt);
    const size_t koff = (size_t)(kt + 1) << 6;

    // ---- phase 0: read A(m0-3)+B(n0-1); stage next A halves ----
#pragma unroll
    for (int i = 0; i < 4; ++i)
#pragma unroll
      for (int ks = 0; ks < 2; ++ks)
        aF[i][ks] = frag_ld(sa, wr * 128 + i * 16 + r16, ks * 32 + hk * 8);
#pragma unroll
    for (int j = 0; j < 2; ++j)
#pragma unroll
      for (int ks = 0; ks < 2; ++ks)
        bF0[j][ks] = frag_ld(sb, wc * 64 + j * 16 + r16, ks * 32 + hk * 8);
    if (pf) {
      stage_half(Ab + koff,                   K, na,            wv, lane);
      stage_half(Ab + 128 * (size_t)K + koff, K, na + 128 * 64, wv, lane);
    }
    __builtin_amdgcn_s_barrier();
    __builtin_amdgcn_s_setprio(1);
#pragma unroll
    for (int i = 0; i < 4; ++i)
#pragma unroll
      for (int j = 0; j < 2; ++j)
#pragma unroll
        for (int ks = 0; ks < 2; ++ks)
          acc[i][j] = __builtin_amdgcn_mfma_f32_16x16x32_bf16(bF0[j][ks], aF[i][ks], acc[i][j], 0, 0, 0);
    __builtin_amdgcn_s_setprio(0);
    __builtin_amdgcn_s_barrier();

    // ---- phase 1: read B(n2-3); stage next B halves ----
#pragma unroll
    for (int j = 0; j < 2; ++j)
#pragma unroll
      for (int ks = 0; ks < 2; ++ks)
        bF1[j][ks] = frag_ld(sb, wc * 64 + (2 + j) * 16 + r16, ks * 32 + hk * 8);
    if (pf) {
      stage_half(Bb + koff,                   K, nb,            wv, lane);
      stage_half(Bb + 128 * (size_t)K + koff, K, nb + 128 * 64, wv, lane);
    }
    __builtin_amdgcn_s_barrier();
    __builtin_amdgcn_s_setprio(1);
#pragma unroll
    for (int i = 0; i < 4; ++i)
#pragma unroll
      for (int j = 0; j < 2; ++j)
#pragma unroll
        for (int ks = 0; ks < 2; ++ks)
          acc[i][2 + j] = __builtin_amdgcn_mfma_f32_16x16x32_bf16(bF1[j][ks], aF[i][ks], acc[i][2 + j], 0, 0, 0);
    __builtin_amdgcn_s_setprio(0);
    __builtin_amdgcn_s_barrier();

    // ---- phase 2: read A(m4-7) ----
#pragma unroll
    for (int i = 0; i < 4; ++i)
#pragma unroll
      for (int ks = 0; ks < 2; ++ks)
        aF[i][ks] = frag_ld(sa, wr * 128 + (4 + i) * 16 + r16, ks * 32 + hk * 8);
    __builtin_amdgcn_s_barrier();
    __builtin_amdgcn_s_setprio(1);
#pragma unroll
    for (int i = 0; i < 4; ++i)
#pragma unroll
      for (int j = 0; j < 2; ++j)
#pragma unroll
        for (int ks = 0; ks < 2; ++ks)
          acc[4 + i][2 + j] = __builtin_amdgcn_mfma_f32_16x16x32_bf16(bF1[j][ks], aF[i][ks], acc[4 + i][2 + j], 0, 0, 0);
    __builtin_amdgcn_s_setprio(0);
    __builtin_amdgcn_s_barrier();

    // ---- phase 3: compute; then K-tile boundary drain ----
    __builtin_amdgcn_s_setprio(1);
#pragma unroll
    for (int i = 0; i < 4; ++i)
#pragma unroll
      for (int j = 0; j < 2; ++j)
#pragma unroll
        for (int ks = 0; ks < 2; ++ks)
          acc[4 + i][j] = __builtin_amdgcn_mfma_f32_16x16x32_bf16(bF0[j][ks], aF[i][ks], acc[4 + i][j], 0, 0, 0);
    __builtin_amdgcn_s_setprio(0);
    asm volatile("s_waitcnt vmcnt(0)" ::: "memory");
    __builtin_amdgcn_s_barrier();
  }

  // ---- epilogue: lane holds C[row=r16+m*16][col=hk*4+r+n*16] (swapped mfma) ----
#pragma unroll
  for (int m = 0; m < 8; ++m) {
    int row = row0 + wr * 128 + m * 16 + r16;
#pragma unroll
    for (int n = 0; n < 4; ++n) {
      int col = col0 + wc * 64 + n * 16 + hk * 4;
      f32x4 b4 = *(const f32x4*)&bias[col];
      f32x4 v;
#pragma unroll
      for (int r = 0; r < 4; ++r) v[r] = acc[m][n][r] + b4[r];
      if (RES == 1) {
        f32x4 rr = *(const f32x4*)&resf[(size_t)row * N + col];
#pragma unroll
        for (int r = 0; r < 4; ++r) v[r] += rr[r];
      }
      if (RES == 2) {
        bf16x4 rb = *(const bf16x4*)&resb[(size_t)row * N + col];
#pragma unroll
        for (int r = 0; r < 4; ++r) v[r] += (float)rb[r];
      }
      bf16x4 o;
#pragma unroll
      for (int r = 0; r < 4; ++r) {
        float x = v[r];
        if (GELU) x = gelu_tanh(x);
        o[r] = (bf16)x;
      }
      *(bf16x4*)&C[(size_t)row * N + col] = o;
    }
  }
}

// ---------------------------------------------------------------- attention
// one block per (b,h); L=64, dh=64. ctx may alias q.
__global__ __launch_bounds__(256) void attn_k(
    const bf16* q, const bf16* __restrict__ k,
    const bf16* __restrict__ v, const float* __restrict__ rel,
    bf16* ctx) {
  __shared__ alignas(16) bf16 lQ[64 * 64];
  __shared__ alignas(16) bf16 lK[64 * 64];
  __shared__ alignas(16) bf16 lVt[64 * 64];
  __shared__ alignas(16) bf16 lP[4][16 * 64];
  __shared__ float lrel[128];

  const int bh = blockIdx.x;
  const int b = bh >> 4, h = bh & 15;
  const int tid = threadIdx.x;
  const size_t base = (size_t)(b * 64) * DMODEL + h * 64;

#pragma unroll
  for (int i = 0; i < 2; ++i) {
    int j = (tid >> 3) + i * 32;
    int d0 = (tid & 7) * 8;
    *(bf16x8*)&lQ[j * 64 + d0] = *(const bf16x8*)(q + base + (size_t)j * DMODEL + d0);
    *(bf16x8*)&lK[j * 64 + d0] = *(const bf16x8*)(k + base + (size_t)j * DMODEL + d0);
    bf16x8 vvv = *(const bf16x8*)(v + base + (size_t)j * DMODEL + d0);
#pragma unroll
    for (int u = 0; u < 8; ++u) lVt[(d0 + u) * 64 + j] = vvv[u];
  }
  if (tid < 127) lrel[tid] = rel[h * 127 + tid];
  __syncthreads();

  const int lane = tid & 63, w = tid >> 6;
  const int r16 = lane & 15, hk = lane >> 4;

  f32x4 s[4] = {};
#pragma unroll
  for (int dstep = 0; dstep < 2; ++dstep) {
    bf16x8 aq = *(const bf16x8*)&lQ[(w * 16 + r16) * 64 + dstep * 32 + hk * 8];
#pragma unroll
    for (int n = 0; n < 4; ++n) {
      bf16x8 bk_ = *(const bf16x8*)&lK[(n * 16 + r16) * 64 + dstep * 32 + hk * 8];
      s[n] = __builtin_amdgcn_mfma_f32_16x16x32_bf16(aq, bk_, s[n], 0, 0, 0);
    }
  }

  float p[16];
#pragma unroll
  for (int n = 0; n < 4; ++n)
#pragma unroll
    for (int r = 0; r < 4; ++r) {
      int i = w * 16 + hk * 4 + r;
      int j = n * 16 + r16;
      p[n * 4 + r] = s[n][r] * 0.125f + lrel[i - j + 63];
    }
#pragma unroll
  for (int r = 0; r < 4; ++r) {
    float m = fmaxf(fmaxf(p[r], p[4 + r]), fmaxf(p[8 + r], p[12 + r]));
#pragma unroll
    for (int off = 1; off < 16; off <<= 1) m = fmaxf(m, __shfl_xor(m, off));
    float sum = 0.f;
#pragma unroll
    for (int n = 0; n < 4; ++n) {
      p[n * 4 + r] = __expf(p[n * 4 + r] - m);
      sum += p[n * 4 + r];
    }
#pragma unroll
    for (int off = 1; off < 16; off <<= 1) sum += __shfl_xor(sum, off);
    float inv = 1.0f / sum;
#pragma unroll
    for (int n = 0; n < 4; ++n) p[n * 4 + r] *= inv;
  }
#pragma unroll
  for (int n = 0; n < 4; ++n)
#pragma unroll
    for (int r = 0; r < 4; ++r)
      lP[w][(hk * 4 + r) * 64 + n * 16 + r16] = (bf16)p[n * 4 + r];
  __syncthreads();

  f32x4 o[4] = {};
#pragma unroll
  for (int ks = 0; ks < 2; ++ks) {
    bf16x8 ap = *(const bf16x8*)&lP[w][r16 * 64 + ks * 32 + hk * 8];
#pragma unroll
    for (int n = 0; n < 4; ++n) {
      bf16x8 bv_ = *(const bf16x8*)&lVt[(n * 16 + r16) * 64 + ks * 32 + hk * 8];
      o[n] = __builtin_amdgcn_mfma_f32_16x16x32_bf16(ap, bv_, o[n], 0, 0, 0);
    }
  }
#pragma unroll
  for (int n = 0; n < 4; ++n)
#pragma unroll
    for (int r = 0; r < 4; ++r) {
      int trow = b * 64 + w * 16 + hk * 4 + r;
      ctx[(size_t)trow * DMODEL + h * 64 + n * 16 + r16] = (bf16)o[n][r];
    }
}

// ---------------------------------------------------------------- layernorm
template <int F32OUT>
__global__ __launch_bounds__(256) void layernorm_k(
    const bf16* __restrict__ x, const float* __restrict__ g,
    const float* __restrict__ be, bf16* __restrict__ ob,
    float* __restrict__ of) {
  int row = blockIdx.x * 4 + (threadIdx.x >> 6);
  int lane = threadIdx.x & 63;
  const bf16* xr = x + (size_t)row * DMODEL + lane * 16;
  bf16x8 v0 = *(const bf16x8*)xr;
  bf16x8 v1 = *(const bf16x8*)(xr + 8);
  float f[16];
#pragma unroll
  for (int j = 0; j < 8; ++j) { f[j] = (float)v0[j]; f[8 + j] = (float)v1[j]; }
  float s = 0.f, sq = 0.f;
#pragma unroll
  for (int j = 0; j < 16; ++j) { s += f[j]; sq += f[j] * f[j]; }
#pragma unroll
  for (int off = 1; off < 64; off <<= 1) {
    s += __shfl_xor(s, off);
    sq += __shfl_xor(sq, off);
  }
  float mean = s * (1.0f / DMODEL);
  float var = sq * (1.0f / DMODEL) - mean * mean;
  float rstd = rsqrtf(var + 1e-5f);
  const float* gp = g + lane * 16;
  const float* bp = be + lane * 16;
  if (F32OUT) {
    float* op = of + (size_t)row * DMODEL + lane * 16;
#pragma unroll
    for (int j = 0; j < 16; ++j)
      op[j] = (f[j] - mean) * rstd * gp[j] + bp[j];
  } else {
    bf16x8 o0, o1;
#pragma unroll
    for (int j = 0; j < 8; ++j) {
      o0[j] = (bf16)((f[j] - mean) * rstd * gp[j] + bp[j]);
      o1[j] = (bf16)((f[8 + j] - mean) * rstd * gp[8 + j] + bp[8 + j]);
    }
    bf16* op = ob + (size_t)row * DMODEL + lane * 16;
    *(bf16x8*)op = o0;
    *(bf16x8*)(op + 8) = o1;
  }
}

// ---------------------------------------------------------------- launch
extern "C" void kernel_launch(void* const* d_in, const int* in_sizes, int n_in,
                              void* d_out, int out_size, void* d_ws, size_t ws_size,
                              hipStream_t stream) {
  (void)in_sizes; (void)n_in; (void)out_size; (void)ws_size;
  const float* src = (const float*)d_in[0];
  const float* Wq  = (const float*)d_in[1];
  const float* bq  = (const float*)d_in[2];
  const float* Wk  = (const float*)d_in[3];
  const float* bk  = (const float*)d_in[4];
  const float* Wv  = (const float*)d_in[5];
  const float* bv  = (const float*)d_in[6];
  const float* Wo  = (const float*)d_in[7];
  const float* bo  = (const float*)d_in[8];
  const float* rel = (const float*)d_in[9];
  const float* W1  = (const float*)d_in[10];
  const float* b1  = (const float*)d_in[11];
  const float* W2  = (const float*)d_in[12];
  const float* b2  = (const float*)d_in[13];
  const float* g1  = (const float*)d_in[14];
  const float* be1 = (const float*)d_in[15];
  const float* g2  = (const float*)d_in[16];
  const float* be2 = (const float*)d_in[17];

  // ws plan (<= 88 MiB, proven safe):
  //   REGION0 = ws[0:64MiB]  : srcb[0:32] + qb[32:64]; later hbuf (64 MiB); later LN2 fp32 out
  //   weights  ws[64:88MiB]
  // d_out (64 MiB fp32) doubles as bf16 scratch:
  //   DO0 = d_out[0:32MiB]  : k, then y1, then y2
  //   DO1 = d_out[32:64MiB] : v, then x (LN1 out)
  char* ws = (char*)d_ws;
  const size_t MiB = 1ull << 20;
  bf16* srcb = (bf16*)(ws + 0 * MiB);
  bf16* qb   = (bf16*)(ws + 32 * MiB);
  bf16* WqT  = (bf16*)(ws + 64 * MiB);
  bf16* WkT  = (bf16*)(ws + 66 * MiB);
  bf16* WvT  = (bf16*)(ws + 68 * MiB);
  bf16* WoT  = (bf16*)(ws + 70 * MiB);
  bf16* W1T  = (bf16*)(ws + 72 * MiB);
  bf16* W2T  = (bf16*)(ws + 80 * MiB);
  bf16* hbuf = (bf16*)(ws + 0 * MiB);     // 64 MiB, after srcb/qb dead
  float* lnout = (float*)(ws + 0 * MiB);  // 64 MiB fp32, after hbuf dead
  bf16* kb = (bf16*)d_out;
  bf16* vb = (bf16*)((char*)d_out + 32 * MiB);
  bf16* y1 = kb;   // after k dead
  bf16* xb = vb;   // after v dead
  bf16* y2 = kb;   // after y1 dead

  cvt_copy<<<(N_TOK * DMODEL) / 2048, 256, 0, stream>>>(src, srcb);
  dim3 tb(32, 8);
  convt<<<dim3(32, 32), tb, 0, stream>>>(Wq, WqT, 1024, 1024);
  convt<<<dim3(32, 32), tb, 0, stream>>>(Wk, WkT, 1024, 1024);
  convt<<<dim3(32, 32), tb, 0, stream>>>(Wv, WvT, 1024, 1024);
  convt<<<dim3(32, 32), tb, 0, stream>>>(Wo, WoT, 1024, 1024);
  convt<<<dim3(128, 32), tb, 0, stream>>>(W1, W1T, 1024, 4096);
  convt<<<dim3(32, 128), tb, 0, stream>>>(W2, W2T, 4096, 1024);

  const int gQKV = (N_TOK / 256) * (DMODEL / 256);   // 64*4 = 256
  gemm256<0, 0><<<gQKV, 512, 0, stream>>>(srcb, WqT, bq, nullptr, nullptr, qb, N_TOK, DMODEL, DMODEL);
  gemm256<0, 0><<<gQKV, 512, 0, stream>>>(srcb, WkT, bk, nullptr, nullptr, kb, N_TOK, DMODEL, DMODEL);
  gemm256<0, 0><<<gQKV, 512, 0, stream>>>(srcb, WvT, bv, nullptr, nullptr, vb, N_TOK, DMODEL, DMODEL);

  attn_k<<<256 * NHEAD, 256, 0, stream>>>(qb, kb, vb, rel, qb);

  // y1 = ctx @ Wo + bo + src (fp32 residual) -> DO0
  gemm256<1, 0><<<gQKV, 512, 0, stream>>>(qb, WoT, bo, src, nullptr, y1, N_TOK, DMODEL, DMODEL);
  // x = LN1(y1) -> DO1
  layernorm_k<0><<<N_TOK / 4, 256, 0, stream>>>(y1, g1, be1, xb, nullptr);

  // FFN in 2 chunks of 8192 rows; h (8192x4096 bf16 = 64 MiB) in REGION0
  const int CH = 8192;
  const int gF1 = (CH / 256) * (FDIM / 256);     // 32*16 = 512
  const int gF2 = (CH / 256) * (DMODEL / 256);   // 32*4  = 128
  for (int c = 0; c < 2; ++c) {
    const bf16* xc = xb + (size_t)c * CH * DMODEL;
    bf16* yc = y2 + (size_t)c * CH * DMODEL;
    gemm256<0, 1><<<gF1, 512, 0, stream>>>(xc, W1T, b1, nullptr, nullptr, hbuf, CH, FDIM, DMODEL);
    gemm256<2, 0><<<gF2, 512, 0, stream>>>(hbuf, W2T, b2, nullptr, xc, yc, CH, DMODEL, FDIM);
  }
  // LN2(y2) -> fp32 in REGION0, then d2d copy to d_out
  layernorm_k<1><<<N_TOK / 4, 256, 0, stream>>>(y2, g2, be2, nullptr, lnout);
  hipMemcpyAsync(d_out, lnout, (size_t)N_TOK * DMODEL * 4, hipMemcpyDeviceToDevice, stream);
}